// Round 1
// baseline (260.806 us; speedup 1.0000x reference)
//
#include <hip/hip_runtime.h>

// VQ-VAE vector quantizer forward, MI355X fp32.
// x: [B=32, C=64, H=64, W=64] fp32; emb: [K=512, D=64] fp32.
// out flat order is (b, h*w, c): out[g*64 + c] = emb[argmin_k dist(g,k)][c],
// g = b*4096 + h*64 + w  (reference reshapes [B*HW,C] directly to x.shape).

#define HWD 4096   // H*W
#define CD  64     // C == D
#define KD  512    // num_embeddings

__global__ void vq_esq_kernel(const float* __restrict__ emb, float* __restrict__ esq) {
    int k = blockIdx.x * blockDim.x + threadIdx.x;
    if (k < KD) {
        const float* er = emb + k * CD;
        float s = 0.f;
        #pragma unroll
        for (int c = 0; c < CD; ++c) s = fmaf(er[c], er[c], s);
        esq[k] = s;
    }
}

__launch_bounds__(256)
__global__ void vq_main_kernel(const float* __restrict__ x,
                               const float* __restrict__ emb,
                               const float* __restrict__ esq,
                               float* __restrict__ out) {
    const int lane = threadIdx.x & 63;
    // readfirstlane: make wave id PROVABLY uniform so emb-row loads become s_load
    const int wave = __builtin_amdgcn_readfirstlane(threadIdx.x >> 6);
    const int tile = blockIdx.x;          // [0, 2048): 64 positions per block
    const int g0   = tile << 6;           // first flat position (b*4096 + n)
    const int b    = g0 >> 12;            // / 4096 (tiles never straddle b)
    const int n0   = g0 & 4095;

    // Coalesced x load: lane i reads position g0+i, looping over c (stride HW)
    const float* xb = x + (size_t)b * (CD * HWD) + n0 + lane;
    float xv[CD];
    #pragma unroll
    for (int c = 0; c < CD; ++c) xv[c] = xb[(size_t)c * HWD];

    // Each wave covers a k-quarter; strict < keeps lowest k on ties (jnp.argmin)
    const int kbase = wave * (KD / 4);
    float bestd = 3.4e38f;
    int   bestk = kbase;
    for (int k = kbase; k < kbase + KD / 4; ++k) {
        const float* er = emb + k * CD;   // wave-uniform -> scalar loads
        float a0 = 0.f, a1 = 0.f, a2 = 0.f, a3 = 0.f;
        #pragma unroll
        for (int c = 0; c < CD; c += 4) {
            a0 = fmaf(xv[c + 0], er[c + 0], a0);
            a1 = fmaf(xv[c + 1], er[c + 1], a1);
            a2 = fmaf(xv[c + 2], er[c + 2], a2);
            a3 = fmaf(xv[c + 3], er[c + 3], a3);
        }
        float dot = (a0 + a1) + (a2 + a3);
        float d   = fmaf(-2.f, dot, esq[k]);   // x_sq constant per position: argmin-invariant
        if (d < bestd) { bestd = d; bestk = k; }
    }

    // Merge the 4 k-quarters (ascending wave order preserves lowest-k ties)
    __shared__ float sh_d[4][64];
    __shared__ int   sh_k[4][64];
    __shared__ int   sh_bk[64];
    sh_d[wave][lane] = bestd;
    sh_k[wave][lane] = bestk;
    __syncthreads();
    if (wave == 0) {
        float bd = sh_d[0][lane];
        int   bk = sh_k[0][lane];
        #pragma unroll
        for (int w = 1; w < 4; ++w) {
            float dw = sh_d[w][lane];
            int   kw = sh_k[w][lane];
            if (dw < bd) { bd = dw; bk = kw; }
        }
        sh_bk[lane] = bk;
    }
    __syncthreads();

    // Cooperative coalesced write: each wave writes one position per iteration
    // (256 B contiguous per wave; emb row read is coalesced + L2-hot)
    #pragma unroll
    for (int it = 0; it < 16; ++it) {
        int p  = (it << 2) + wave;        // wave-uniform position in tile
        int bk = sh_bk[p];                // LDS broadcast read
        out[(size_t)(g0 + p) * CD + lane] = emb[bk * CD + lane];
    }
}

extern "C" void kernel_launch(void* const* d_in, const int* in_sizes, int n_in,
                              void* d_out, int out_size, void* d_ws, size_t ws_size,
                              hipStream_t stream) {
    const float* x   = (const float*)d_in[0];   // 32*64*64*64
    const float* emb = (const float*)d_in[1];   // 512*64
    float* out = (float*)d_out;                 // 8388608 floats
    float* esq = (float*)d_ws;                  // 512 floats scratch

    vq_esq_kernel<<<2, 256, 0, stream>>>(emb, esq);
    vq_main_kernel<<<2048, 256, 0, stream>>>(x, emb, esq, out);
}